// Round 5
// baseline (614.290 us; speedup 1.0000x reference)
//
#include <hip/hip_runtime.h>
#include <hip/hip_bf16.h>

#define U_CNT 339
#define S_CNT 5825
#define N_CNT 6164          // U + S
#define D_DIM 128
#define R_DIM 32
#define B_CNT 500000
#define M_EDGE 400000       // 2*NNZ (symmetrized)
#define H_DIM 64
#define LN_EPS 1e-5f

// fp32 weight-block offsets (elements)
#define WF_W2   0
#define WF_B1   4096
#define WF_G1   4160
#define WF_BE1  4224
#define WF_B2   4288
#define WF_G2   4352
#define WF_BE2  4416
#define WF_W3   4480
#define WF_B3   4544
#define WF_TOT  4545

typedef __hip_bfloat16 bf16;

__device__ __forceinline__ float b2f(bf16 x) { return __bfloat162float(x); }

// generic float-input load: isf32 selects fp32 vs bf16 interpretation
__device__ __forceinline__ float ldf(const void* p, long i, int isf32) {
    return isf32 ? ((const float*)p)[i] : b2f(((const bf16*)p)[i]);
}

// ---------- init: zero counts/fill + dtype detect (block 0, wave 0) ----------
__global__ void k_init(const void* __restrict__ uE, int* __restrict__ counts,
                       int* __restrict__ fill, int* __restrict__ flag) {
    int i = blockIdx.x * 256 + threadIdx.x;
    if (i < N_CNT) { counts[i] = 0; fill[i] = 0; }
    if (blockIdx.x == 0 && threadIdx.x < 64) {
        const unsigned short* p = (const unsigned short*)uE;
        unsigned short v = p[2 * threadIdx.x];       // even bf16 element
        int e = (v >> 7) & 0xFF;                     // bf16 exponent field
        unsigned long long m = __ballot(e >= 127);   // impossible for Xavier bf16
        if (threadIdx.x == 0) flag[0] = (m != 0ull) ? 1 : 0;  // 1 => fp32 buffers
    }
}

// ---------- concat embeddings to fp32 [N,D] + edge histogram (fused) ----------
__global__ void k_pre(const void* __restrict__ uE, const void* __restrict__ iE,
                      float* __restrict__ E, const int* __restrict__ rows,
                      int* __restrict__ counts, const int* __restrict__ flag) {
    int i = blockIdx.x * 256 + threadIdx.x;
    int isf32 = flag[0];
    const int T1 = N_CNT * D_DIM;
    if (i < T1) {
        const int uTot = U_CNT * D_DIM;
        E[i] = (i < uTot) ? ldf(uE, i, isf32) : ldf(iE, i - uTot, isf32);
    }
    if (i < M_EDGE) atomicAdd(&counts[rows[i]], 1);
}

// ---------- CSR build: exclusive scan over N=6164 counts (one 256-thread block) ----------
__global__ void k_scan(const int* __restrict__ counts, int* __restrict__ row_ptr) {
    __shared__ int part[256];
    const int RPT = 25;                               // 256*25 = 6400 >= N+1
    int t = threadIdx.x;
    int base = t * RPT;
    int local[RPT];
    int s = 0;
    #pragma unroll
    for (int i = 0; i < RPT; ++i) {
        int idx = base + i;
        int v = (idx < N_CNT) ? counts[idx] : 0;
        local[i] = s;
        s += v;
    }
    part[t] = s;
    __syncthreads();
    for (int off = 1; off < 256; off <<= 1) {
        int v = (t >= off) ? part[t - off] : 0;
        __syncthreads();
        part[t] += v;
        __syncthreads();
    }
    int prefix = (t > 0) ? part[t - 1] : 0;
    #pragma unroll
    for (int i = 0; i < RPT; ++i) {
        int idx = base + i;
        if (idx <= N_CNT) row_ptr[idx] = prefix + local[i];
    }
}

// ---------- CSR build: scatter edges, packed int2{col, val_bits} ----------
__global__ void k_scatter(const int* __restrict__ rows, const int* __restrict__ cols,
                          const void* __restrict__ vals, const int* __restrict__ row_ptr,
                          int* __restrict__ fill, int2* __restrict__ csr,
                          const int* __restrict__ flag) {
    int e = blockIdx.x * 256 + threadIdx.x;
    if (e >= M_EDGE) return;
    int isf32 = flag[0];
    int r = rows[e];
    int pos = atomicAdd(&fill[r], 1);
    int o = row_ptr[r] + pos;
    float v = ldf(vals, e, isf32);
    csr[o] = make_int2(cols[e], __float_as_int(v));
}

// ---------- SpMM gather, float2 lanes, packed edges, unroll-4 ----------
__global__ void k_spmm(const float2* __restrict__ Ein2, float2* __restrict__ Eout2,
                       const int* __restrict__ row_ptr, const int2* __restrict__ csr) {
    int r = blockIdx.x;
    int d = threadIdx.x;                              // 0..63, two dims per lane
    int k0 = row_ptr[r], k1 = row_ptr[r + 1];
    float ax0 = 0, ay0 = 0, ax1 = 0, ay1 = 0, ax2 = 0, ay2 = 0, ax3 = 0, ay3 = 0;
    int k = k0;
    for (; k + 4 <= k1; k += 4) {
        int2 e0 = csr[k], e1 = csr[k + 1], e2 = csr[k + 2], e3 = csr[k + 3];
        float2 f0 = Ein2[e0.x * 64 + d], f1 = Ein2[e1.x * 64 + d];
        float2 f2 = Ein2[e2.x * 64 + d], f3 = Ein2[e3.x * 64 + d];
        float v0 = __int_as_float(e0.y), v1 = __int_as_float(e1.y);
        float v2 = __int_as_float(e2.y), v3 = __int_as_float(e3.y);
        ax0 = fmaf(v0, f0.x, ax0); ay0 = fmaf(v0, f0.y, ay0);
        ax1 = fmaf(v1, f1.x, ax1); ay1 = fmaf(v1, f1.y, ay1);
        ax2 = fmaf(v2, f2.x, ax2); ay2 = fmaf(v2, f2.y, ay2);
        ax3 = fmaf(v3, f3.x, ax3); ay3 = fmaf(v3, f3.y, ay3);
    }
    for (; k < k1; ++k) {
        int2 e = csr[k];
        float v = __int_as_float(e.y);
        float2 f = Ein2[e.x * 64 + d];
        ax0 = fmaf(v, f.x, ax0); ay0 = fmaf(v, f.y, ay0);
    }
    float2 o;
    o.x = (ax0 + ax1) + (ax2 + ax3);
    o.y = (ay0 + ay1) + (ay2 + ay3);
    Eout2[r * 64 + d] = o;
}

// ---------- blocks 0,1: P = Hyperᵀ(Hyper @ W1part); block 2: weights→fp32 ----------
__global__ void k_hyperP(const void* __restrict__ uHy, const void* __restrict__ iHy,
                         const void* __restrict__ W1, const void* __restrict__ W2,
                         const void* __restrict__ b1, const void* __restrict__ g1,
                         const void* __restrict__ be1, const void* __restrict__ b2,
                         const void* __restrict__ g2, const void* __restrict__ be2,
                         const void* __restrict__ W3, const void* __restrict__ b3,
                         float* __restrict__ P, float* __restrict__ Wf,
                         const int* __restrict__ flag) {
    int isf32 = flag[0];
    if (blockIdx.x == 2) {                            // weight prep
        for (int i = threadIdx.x; i < WF_TOT; i += 256) {
            float v;
            if      (i < WF_B1)  v = ldf(W2,  i,           isf32);
            else if (i < WF_G1)  v = ldf(b1,  i - WF_B1,   isf32);
            else if (i < WF_BE1) v = ldf(g1,  i - WF_G1,   isf32);
            else if (i < WF_B2)  v = ldf(be1, i - WF_BE1,  isf32);
            else if (i < WF_G2)  v = ldf(b2,  i - WF_B2,   isf32);
            else if (i < WF_BE2) v = ldf(g2,  i - WF_G2,   isf32);
            else if (i < WF_W3)  v = ldf(be2, i - WF_BE2,  isf32);
            else if (i < WF_B3)  v = ldf(W3,  i - WF_W3,   isf32);
            else                 v = ldf(b3,  0,           isf32);
            Wf[i] = v;
        }
        return;
    }
    int side = blockIdx.x;                            // 0 = user, 1 = service
    const void* Hy = side ? iHy : uHy;                // [32][128]
    long wbase = (long)side * D_DIM * H_DIM;          // rows [side*128 .. +128) of W1
    __shared__ float Hs[R_DIM * D_DIM];               // 16 KB
    __shared__ float T[R_DIM * H_DIM];                // 8 KB
    for (int idx = threadIdx.x; idx < R_DIM * D_DIM; idx += 256)
        Hs[idx] = ldf(Hy, idx, isf32);
    __syncthreads();
    for (int idx = threadIdx.x; idx < R_DIM * H_DIM; idx += 256) {
        int a = idx >> 6, j = idx & 63;
        float acc = 0.f;
        for (int d = 0; d < D_DIM; ++d)
            acc = fmaf(Hs[a * D_DIM + d], ldf(W1, wbase + d * H_DIM + j, isf32), acc);
        T[idx] = acc;
    }
    __syncthreads();
    for (int idx = threadIdx.x; idx < D_DIM * H_DIM; idx += 256) {
        int d = idx >> 6, j = idx & 63;
        float acc = 0.f;
        #pragma unroll
        for (int a = 0; a < R_DIM; ++a)
            acc = fmaf(Hs[a * D_DIM + d], T[a * H_DIM + j], acc);
        P[side * D_DIM * H_DIM + idx] = acc;
    }
}

// ---------- A[r,:] = E[r,:] @ P(side) (+ b1 folded into user rows) ----------
__global__ void k_A(const float* __restrict__ E, const float* __restrict__ P,
                    const float* __restrict__ Wf, float* __restrict__ A) {
    int r = blockIdx.x;
    int j = threadIdx.x;                              // 64 threads
    const float* Pr = P + ((r < U_CNT) ? 0 : D_DIM * H_DIM);
    const float* Er = E + r * D_DIM;                  // wave-uniform -> scalar loads
    float acc = (r < U_CNT) ? Wf[WF_B1 + j] : 0.f;
    #pragma unroll 8
    for (int d = 0; d < D_DIM; ++d)
        acc = fmaf(Er[d], Pr[d * H_DIM + j], acc);
    A[r * H_DIM + j] = acc;
}

// ---------- fused MLP: ONE ROW PER THREAD, z and y both register-resident ----------
// __launch_bounds__(256, 2): permit up to 256 VGPR so the compiler keeps
// z[64]+y[64] live instead of re-loading A inside the W2 loop (R4: 68 VGPR,
// VALUBusy 44%, reload-stalled at 86 us).
__global__ void __launch_bounds__(256, 2)
HyperModel_65755949301857_kernel(
      const float* __restrict__ A, const int* __restrict__ userIdx,
      const int* __restrict__ servIdx, const float* __restrict__ Wf,
      void* __restrict__ out, const int* __restrict__ flag) {
    int b = blockIdx.x * 256 + threadIdx.x;
    if (b >= B_CNT) return;
    int isf32 = flag[0];
    int ui = userIdx[b];
    int si = servIdx[b] + U_CNT;
    const float4* A4 = (const float4*)A;

    // z = A_u[ui] + A_s[si]  (b1 pre-folded into A_u) -- gathered ONCE
    float4 za[16];
    #pragma unroll
    for (int q = 0; q < 16; ++q) {
        float4 a = A4[ui * 16 + q];
        float4 s = A4[si * 16 + q];
        za[q].x = a.x + s.x;
        za[q].y = a.y + s.y;
        za[q].z = a.z + s.z;
        za[q].w = a.w + s.w;
    }
    // LayerNorm 1 (in-register tree sums)
    float s0 = 0, s1 = 0, s2 = 0, s3 = 0, q0 = 0, q1 = 0, q2 = 0, q3 = 0;
    #pragma unroll
    for (int q = 0; q < 16; ++q) {
        s0 += za[q].x; q0 = fmaf(za[q].x, za[q].x, q0);
        s1 += za[q].y; q1 = fmaf(za[q].y, za[q].y, q1);
        s2 += za[q].z; q2 = fmaf(za[q].z, za[q].z, q2);
        s3 += za[q].w; q3 = fmaf(za[q].w, za[q].w, q3);
    }
    float mu  = ((s0 + s1) + (s2 + s3)) * (1.f / 64.f);
    float ex2 = ((q0 + q1) + (q2 + q3)) * (1.f / 64.f);
    float rs = rsqrtf(ex2 - mu * mu + LN_EPS);
    float nmrs = -mu * rs;
    #pragma unroll
    for (int q = 0; q < 16; ++q) {
        za[q].x = fmaxf(fmaf(fmaf(za[q].x, rs, nmrs), Wf[WF_G1 + 4 * q + 0], Wf[WF_BE1 + 4 * q + 0]), 0.f);
        za[q].y = fmaxf(fmaf(fmaf(za[q].y, rs, nmrs), Wf[WF_G1 + 4 * q + 1], Wf[WF_BE1 + 4 * q + 1]), 0.f);
        za[q].z = fmaxf(fmaf(fmaf(za[q].z, rs, nmrs), Wf[WF_G1 + 4 * q + 2], Wf[WF_BE1 + 4 * q + 2]), 0.f);
        za[q].w = fmaxf(fmaf(fmaf(za[q].w, rs, nmrs), Wf[WF_G1 + 4 * q + 3], Wf[WF_BE1 + 4 * q + 3]), 0.f);
    }
    // y = h @ W2 + b2 : weights wave-uniform -> scalar (K$) loads
    float y[64];
    #pragma unroll
    for (int j = 0; j < 64; ++j) y[j] = Wf[WF_B2 + j];
    #pragma unroll
    for (int kq = 0; kq < 16; ++kq) {
        float h0 = za[kq].x, h1 = za[kq].y, h2 = za[kq].z, h3 = za[kq].w;
        const float* w0 = Wf + WF_W2 + (4 * kq + 0) * 64;
        const float* w1 = Wf + WF_W2 + (4 * kq + 1) * 64;
        const float* w2 = Wf + WF_W2 + (4 * kq + 2) * 64;
        const float* w3 = Wf + WF_W2 + (4 * kq + 3) * 64;
        #pragma unroll
        for (int j = 0; j < 64; ++j) {
            float acc = y[j];
            acc = fmaf(h0, w0[j], acc);
            acc = fmaf(h1, w1[j], acc);
            acc = fmaf(h2, w2[j], acc);
            acc = fmaf(h3, w3[j], acc);
            y[j] = acc;
        }
    }
    // LayerNorm 2 + relu + W3 dot
    s0 = s1 = s2 = s3 = q0 = q1 = q2 = q3 = 0;
    #pragma unroll
    for (int j = 0; j < 64; j += 4) {
        s0 += y[j];     q0 = fmaf(y[j],     y[j],     q0);
        s1 += y[j + 1]; q1 = fmaf(y[j + 1], y[j + 1], q1);
        s2 += y[j + 2]; q2 = fmaf(y[j + 2], y[j + 2], q2);
        s3 += y[j + 3]; q3 = fmaf(y[j + 3], y[j + 3], q3);
    }
    mu  = ((s0 + s1) + (s2 + s3)) * (1.f / 64.f);
    ex2 = ((q0 + q1) + (q2 + q3)) * (1.f / 64.f);
    float rs2 = rsqrtf(ex2 - mu * mu + LN_EPS);
    float nmrs2 = -mu * rs2;
    float o0 = 0, o1 = 0, o2 = 0, o3 = 0;
    #pragma unroll
    for (int j = 0; j < 64; j += 4) {
        float t0 = fmaxf(fmaf(fmaf(y[j],     rs2, nmrs2), Wf[WF_G2 + j],     Wf[WF_BE2 + j]),     0.f);
        float t1 = fmaxf(fmaf(fmaf(y[j + 1], rs2, nmrs2), Wf[WF_G2 + j + 1], Wf[WF_BE2 + j + 1]), 0.f);
        float t2 = fmaxf(fmaf(fmaf(y[j + 2], rs2, nmrs2), Wf[WF_G2 + j + 2], Wf[WF_BE2 + j + 2]), 0.f);
        float t3 = fmaxf(fmaf(fmaf(y[j + 3], rs2, nmrs2), Wf[WF_G2 + j + 3], Wf[WF_BE2 + j + 3]), 0.f);
        o0 = fmaf(t0, Wf[WF_W3 + j],     o0);
        o1 = fmaf(t1, Wf[WF_W3 + j + 1], o1);
        o2 = fmaf(t2, Wf[WF_W3 + j + 2], o2);
        o3 = fmaf(t3, Wf[WF_W3 + j + 3], o3);
    }
    float o = ((o0 + o1) + (o2 + o3)) + Wf[WF_B3];
    if (isf32) ((float*)out)[b] = o;
    else       ((bf16*)out)[b] = __float2bfloat16(o);
}

extern "C" __attribute__((visibility("default")))
void kernel_launch(void* const* d_in, const int* in_sizes, int n_in,
                   void* d_out, int out_size, void* d_ws, size_t ws_size,
                   hipStream_t stream) {
    const void* uE   = d_in[0];
    const void* iE   = d_in[1];
    const void* uHy  = d_in[2];
    const void* iHy  = d_in[3];
    const void* W1   = d_in[4];
    const void* b1   = d_in[5];
    const void* g1   = d_in[6];
    const void* be1  = d_in[7];
    const void* W2   = d_in[8];
    const void* b2   = d_in[9];
    const void* g2   = d_in[10];
    const void* be2  = d_in[11];
    const void* W3   = d_in[12];
    const void* b3   = d_in[13];
    const void* adj_vals = d_in[14];
    const int*  adj_rows = (const int*)d_in[15];
    const int*  adj_cols = (const int*)d_in[16];
    const int*  userIdx  = (const int*)d_in[17];
    const int*  servIdx  = (const int*)d_in[18];

    char* w = (char*)d_ws;
    size_t off = 0;
    auto alloc = [&](size_t bytes) -> char* {
        char* p = w + off;
        off += (bytes + 255) & ~(size_t)255;
        return p;
    };
    float* E0      = (float*)alloc((size_t)N_CNT * D_DIM * 4);
    float* E1      = (float*)alloc((size_t)N_CNT * D_DIM * 4);
    float* P       = (float*)alloc((size_t)2 * D_DIM * H_DIM * 4);
    float* A       = (float*)alloc((size_t)N_CNT * H_DIM * 4);
    int2*  csr     = (int2*)alloc((size_t)M_EDGE * 8);
    int*   row_ptr = (int*)alloc((size_t)(N_CNT + 1) * 4);
    int*   counts  = (int*)alloc((size_t)N_CNT * 4);
    int*   fill    = (int*)alloc((size_t)N_CNT * 4);
    int*   flag    = (int*)alloc(256);
    float* Wf      = (float*)alloc((size_t)WF_TOT * 4);

    k_init<<<(N_CNT + 255) / 256, 256, 0, stream>>>(uE, counts, fill, flag);
    k_pre<<<(N_CNT * D_DIM + 255) / 256, 256, 0, stream>>>(uE, iE, E0, adj_rows, counts, flag);
    k_scan<<<1, 256, 0, stream>>>(counts, row_ptr);
    k_scatter<<<(M_EDGE + 255) / 256, 256, 0, stream>>>(adj_rows, adj_cols, adj_vals,
                                                        row_ptr, fill, csr, flag);
    // 3 propagation hops: E0 -> E1 -> E0 -> E1
    k_spmm<<<N_CNT, 64, 0, stream>>>((const float2*)E0, (float2*)E1, row_ptr, csr);
    k_spmm<<<N_CNT, 64, 0, stream>>>((const float2*)E1, (float2*)E0, row_ptr, csr);
    k_spmm<<<N_CNT, 64, 0, stream>>>((const float2*)E0, (float2*)E1, row_ptr, csr);

    k_hyperP<<<3, 256, 0, stream>>>(uHy, iHy, W1, W2, b1, g1, be1, b2, g2, be2, W3, b3,
                                    P, Wf, flag);
    k_A<<<N_CNT, H_DIM, 0, stream>>>(E1, P, Wf, A);

    HyperModel_65755949301857_kernel<<<(B_CNT + 255) / 256, 256, 0, stream>>>(
        A, userIdx, servIdx, Wf, d_out, flag);
}

// Round 6
// 520.519 us; speedup vs baseline: 1.1801x; 1.1801x over previous
//
#include <hip/hip_runtime.h>
#include <hip/hip_bf16.h>

#define U_CNT 339
#define S_CNT 5825
#define N_CNT 6164          // U + S
#define D_DIM 128
#define R_DIM 32
#define B_CNT 500000
#define M_EDGE 400000       // 2*NNZ (symmetrized)
#define H_DIM 64
#define LN_EPS 1e-5f

// fp32 weight-block offsets (elements)
#define WF_W2   0
#define WF_B1   4096
#define WF_G1   4160
#define WF_BE1  4224
#define WF_B2   4288
#define WF_G2   4352
#define WF_BE2  4416
#define WF_W3   4480
#define WF_B3   4544
#define WF_TOT  4545

typedef __hip_bfloat16 bf16;

__device__ __forceinline__ float b2f(bf16 x) { return __bfloat162float(x); }

// generic float-input load: isf32 selects fp32 vs bf16 interpretation
__device__ __forceinline__ float ldf(const void* p, long i, int isf32) {
    return isf32 ? ((const float*)p)[i] : b2f(((const bf16*)p)[i]);
}

// ---------- init: zero counts/fill + dtype detect (block 0, wave 0) ----------
__global__ void k_init(const void* __restrict__ uE, int* __restrict__ counts,
                       int* __restrict__ fill, int* __restrict__ flag) {
    int i = blockIdx.x * 256 + threadIdx.x;
    if (i < N_CNT) { counts[i] = 0; fill[i] = 0; }
    if (blockIdx.x == 0 && threadIdx.x < 64) {
        const unsigned short* p = (const unsigned short*)uE;
        unsigned short v = p[2 * threadIdx.x];       // even bf16 element
        int e = (v >> 7) & 0xFF;                     // bf16 exponent field
        unsigned long long m = __ballot(e >= 127);   // impossible for Xavier bf16
        if (threadIdx.x == 0) flag[0] = (m != 0ull) ? 1 : 0;  // 1 => fp32 buffers
    }
}

// ---------- concat embeddings to fp32 [N,D] + edge histogram (fused) ----------
__global__ void k_pre(const void* __restrict__ uE, const void* __restrict__ iE,
                      float* __restrict__ E, const int* __restrict__ rows,
                      int* __restrict__ counts, const int* __restrict__ flag) {
    int i = blockIdx.x * 256 + threadIdx.x;
    int isf32 = flag[0];
    const int T1 = N_CNT * D_DIM;
    if (i < T1) {
        const int uTot = U_CNT * D_DIM;
        E[i] = (i < uTot) ? ldf(uE, i, isf32) : ldf(iE, i - uTot, isf32);
    }
    if (i < M_EDGE) atomicAdd(&counts[rows[i]], 1);
}

// ---------- CSR build: exclusive scan over N=6164 counts (one 256-thread block) ----------
__global__ void k_scan(const int* __restrict__ counts, int* __restrict__ row_ptr) {
    __shared__ int part[256];
    const int RPT = 25;                               // 256*25 = 6400 >= N+1
    int t = threadIdx.x;
    int base = t * RPT;
    int local[RPT];
    int s = 0;
    #pragma unroll
    for (int i = 0; i < RPT; ++i) {
        int idx = base + i;
        int v = (idx < N_CNT) ? counts[idx] : 0;
        local[i] = s;
        s += v;
    }
    part[t] = s;
    __syncthreads();
    for (int off = 1; off < 256; off <<= 1) {
        int v = (t >= off) ? part[t - off] : 0;
        __syncthreads();
        part[t] += v;
        __syncthreads();
    }
    int prefix = (t > 0) ? part[t - 1] : 0;
    #pragma unroll
    for (int i = 0; i < RPT; ++i) {
        int idx = base + i;
        if (idx <= N_CNT) row_ptr[idx] = prefix + local[i];
    }
}

// ---------- CSR build: scatter edges, packed int2{col, val_bits} ----------
__global__ void k_scatter(const int* __restrict__ rows, const int* __restrict__ cols,
                          const void* __restrict__ vals, const int* __restrict__ row_ptr,
                          int* __restrict__ fill, int2* __restrict__ csr,
                          const int* __restrict__ flag) {
    int e = blockIdx.x * 256 + threadIdx.x;
    if (e >= M_EDGE) return;
    int isf32 = flag[0];
    int r = rows[e];
    int pos = atomicAdd(&fill[r], 1);
    int o = row_ptr[r] + pos;
    float v = ldf(vals, e, isf32);
    csr[o] = make_int2(cols[e], __float_as_int(v));
}

// ---------- SpMM: 4 waves per row split the edge list, LDS reduce ----------
// User rows have deg~590: one wave serial over edges was latency-bound
// (~150 iters x L2 latency). 4 waves give 4x latency parallelism + 4-deep
// unroll gives 4 outstanding 512B row loads per wave.
__global__ void __launch_bounds__(256)
k_spmm(const float2* __restrict__ Ein2, float2* __restrict__ Eout2,
       const int* __restrict__ row_ptr, const int2* __restrict__ csr) {
    __shared__ float2 part[4][64];
    int r = blockIdx.x;
    int wave = threadIdx.x >> 6;
    int d = threadIdx.x & 63;                         // 2 dims per lane
    int k0 = row_ptr[r], k1 = row_ptr[r + 1];
    int cnt = k1 - k0;
    int chunk = (cnt + 3) >> 2;
    int ck0 = k0 + min(wave * chunk, cnt);
    int ck1 = k0 + min((wave + 1) * chunk, cnt);
    float ax0 = 0, ay0 = 0, ax1 = 0, ay1 = 0, ax2 = 0, ay2 = 0, ax3 = 0, ay3 = 0;
    int k = ck0;
    for (; k + 4 <= ck1; k += 4) {
        int2 e0 = csr[k], e1 = csr[k + 1], e2 = csr[k + 2], e3 = csr[k + 3];
        float2 f0 = Ein2[e0.x * 64 + d], f1 = Ein2[e1.x * 64 + d];
        float2 f2 = Ein2[e2.x * 64 + d], f3 = Ein2[e3.x * 64 + d];
        float v0 = __int_as_float(e0.y), v1 = __int_as_float(e1.y);
        float v2 = __int_as_float(e2.y), v3 = __int_as_float(e3.y);
        ax0 = fmaf(v0, f0.x, ax0); ay0 = fmaf(v0, f0.y, ay0);
        ax1 = fmaf(v1, f1.x, ax1); ay1 = fmaf(v1, f1.y, ay1);
        ax2 = fmaf(v2, f2.x, ax2); ay2 = fmaf(v2, f2.y, ay2);
        ax3 = fmaf(v3, f3.x, ax3); ay3 = fmaf(v3, f3.y, ay3);
    }
    for (; k < ck1; ++k) {
        int2 e = csr[k];
        float v = __int_as_float(e.y);
        float2 f = Ein2[e.x * 64 + d];
        ax0 = fmaf(v, f.x, ax0); ay0 = fmaf(v, f.y, ay0);
    }
    float2 o;
    o.x = (ax0 + ax1) + (ax2 + ax3);
    o.y = (ay0 + ay1) + (ay2 + ay3);
    part[wave][d] = o;
    __syncthreads();
    if (wave == 0) {
        float2 a = part[0][d], b = part[1][d], c = part[2][d], e = part[3][d];
        float2 s;
        s.x = (a.x + b.x) + (c.x + e.x);
        s.y = (a.y + b.y) + (c.y + e.y);
        Eout2[r * 64 + d] = s;
    }
}

// ---------- blocks 0,1: P = Hyperᵀ(Hyper @ W1part); block 2: weights→fp32 ----------
__global__ void k_hyperP(const void* __restrict__ uHy, const void* __restrict__ iHy,
                         const void* __restrict__ W1, const void* __restrict__ W2,
                         const void* __restrict__ b1, const void* __restrict__ g1,
                         const void* __restrict__ be1, const void* __restrict__ b2,
                         const void* __restrict__ g2, const void* __restrict__ be2,
                         const void* __restrict__ W3, const void* __restrict__ b3,
                         float* __restrict__ P, float* __restrict__ Wf,
                         const int* __restrict__ flag) {
    int isf32 = flag[0];
    if (blockIdx.x == 2) {                            // weight prep
        for (int i = threadIdx.x; i < WF_TOT; i += 256) {
            float v;
            if      (i < WF_B1)  v = ldf(W2,  i,           isf32);
            else if (i < WF_G1)  v = ldf(b1,  i - WF_B1,   isf32);
            else if (i < WF_BE1) v = ldf(g1,  i - WF_G1,   isf32);
            else if (i < WF_B2)  v = ldf(be1, i - WF_BE1,  isf32);
            else if (i < WF_G2)  v = ldf(b2,  i - WF_B2,   isf32);
            else if (i < WF_BE2) v = ldf(g2,  i - WF_G2,   isf32);
            else if (i < WF_W3)  v = ldf(be2, i - WF_BE2,  isf32);
            else if (i < WF_B3)  v = ldf(W3,  i - WF_W3,   isf32);
            else                 v = ldf(b3,  0,           isf32);
            Wf[i] = v;
        }
        return;
    }
    int side = blockIdx.x;                            // 0 = user, 1 = service
    const void* Hy = side ? iHy : uHy;                // [32][128]
    long wbase = (long)side * D_DIM * H_DIM;          // rows [side*128 .. +128) of W1
    __shared__ float Hs[R_DIM * D_DIM];               // 16 KB
    __shared__ float T[R_DIM * H_DIM];                // 8 KB
    for (int idx = threadIdx.x; idx < R_DIM * D_DIM; idx += 256)
        Hs[idx] = ldf(Hy, idx, isf32);
    __syncthreads();
    for (int idx = threadIdx.x; idx < R_DIM * H_DIM; idx += 256) {
        int a = idx >> 6, j = idx & 63;
        float acc = 0.f;
        for (int d = 0; d < D_DIM; ++d)
            acc = fmaf(Hs[a * D_DIM + d], ldf(W1, wbase + d * H_DIM + j, isf32), acc);
        T[idx] = acc;
    }
    __syncthreads();
    for (int idx = threadIdx.x; idx < D_DIM * H_DIM; idx += 256) {
        int d = idx >> 6, j = idx & 63;
        float acc = 0.f;
        #pragma unroll
        for (int a = 0; a < R_DIM; ++a)
            acc = fmaf(Hs[a * D_DIM + d], T[a * H_DIM + j], acc);
        P[side * D_DIM * H_DIM + idx] = acc;
    }
}

// ---------- A[r,:] = E[r,:] @ P(side) (+ b1 folded into user rows) ----------
__global__ void k_A(const float* __restrict__ E, const float* __restrict__ P,
                    const float* __restrict__ Wf, float* __restrict__ A) {
    int r = blockIdx.x;
    int j = threadIdx.x;                              // 64 threads
    const float* Pr = P + ((r < U_CNT) ? 0 : D_DIM * H_DIM);
    const float* Er = E + r * D_DIM;                  // wave-uniform -> scalar loads
    float acc = (r < U_CNT) ? Wf[WF_B1 + j] : 0.f;
    #pragma unroll 8
    for (int d = 0; d < D_DIM; ++d)
        acc = fmaf(Er[d], Pr[d * H_DIM + j], acc);
    A[r * H_DIM + j] = acc;
}

// ---------- fused MLP: ONE ROW PER THREAD ----------
// amdgpu_waves_per_eu(2,2) PINS occupancy at 2 waves/EU so the register
// allocator has no incentive to stay small: R5 showed that a ceiling alone
// (launch_bounds 2nd arg) leaves the heuristic at 76 VGPR and it RECOMPUTES
// y[] for LN2 (VALUBusy 63% = 2x the 30us floor). With occupancy pinned,
// h[64]+y[64] stay register-resident (~160 VGPR) and y is computed once.
__global__ void __launch_bounds__(256)
__attribute__((amdgpu_waves_per_eu(2, 2)))
HyperModel_65755949301857_kernel(
      const float* __restrict__ A, const int* __restrict__ userIdx,
      const int* __restrict__ servIdx, const float* __restrict__ Wf,
      void* __restrict__ out, const int* __restrict__ flag) {
    int b = blockIdx.x * 256 + threadIdx.x;
    if (b >= B_CNT) return;
    int isf32 = flag[0];
    int ui = userIdx[b];
    int si = servIdx[b] + U_CNT;
    const float4* A4 = (const float4*)A;

    // z = A_u[ui] + A_s[si]  (b1 pre-folded into A_u) -- gathered ONCE
    float4 za[16];
    #pragma unroll
    for (int q = 0; q < 16; ++q) {
        float4 a = A4[ui * 16 + q];
        float4 s = A4[si * 16 + q];
        za[q].x = a.x + s.x;
        za[q].y = a.y + s.y;
        za[q].z = a.z + s.z;
        za[q].w = a.w + s.w;
    }
    // LayerNorm 1 (in-register tree sums)
    float s0 = 0, s1 = 0, s2 = 0, s3 = 0, q0 = 0, q1 = 0, q2 = 0, q3 = 0;
    #pragma unroll
    for (int q = 0; q < 16; ++q) {
        s0 += za[q].x; q0 = fmaf(za[q].x, za[q].x, q0);
        s1 += za[q].y; q1 = fmaf(za[q].y, za[q].y, q1);
        s2 += za[q].z; q2 = fmaf(za[q].z, za[q].z, q2);
        s3 += za[q].w; q3 = fmaf(za[q].w, za[q].w, q3);
    }
    float mu  = ((s0 + s1) + (s2 + s3)) * (1.f / 64.f);
    float ex2 = ((q0 + q1) + (q2 + q3)) * (1.f / 64.f);
    float rs = rsqrtf(ex2 - mu * mu + LN_EPS);
    float nmrs = -mu * rs;
    #pragma unroll
    for (int q = 0; q < 16; ++q) {
        za[q].x = fmaxf(fmaf(fmaf(za[q].x, rs, nmrs), Wf[WF_G1 + 4 * q + 0], Wf[WF_BE1 + 4 * q + 0]), 0.f);
        za[q].y = fmaxf(fmaf(fmaf(za[q].y, rs, nmrs), Wf[WF_G1 + 4 * q + 1], Wf[WF_BE1 + 4 * q + 1]), 0.f);
        za[q].z = fmaxf(fmaf(fmaf(za[q].z, rs, nmrs), Wf[WF_G1 + 4 * q + 2], Wf[WF_BE1 + 4 * q + 2]), 0.f);
        za[q].w = fmaxf(fmaf(fmaf(za[q].w, rs, nmrs), Wf[WF_G1 + 4 * q + 3], Wf[WF_BE1 + 4 * q + 3]), 0.f);
    }
    // y = h @ W2 + b2 : weights wave-uniform -> scalar (K$) loads
    float y[64];
    #pragma unroll
    for (int j = 0; j < 64; ++j) y[j] = Wf[WF_B2 + j];
    #pragma unroll
    for (int kq = 0; kq < 16; ++kq) {
        float h0 = za[kq].x, h1 = za[kq].y, h2 = za[kq].z, h3 = za[kq].w;
        const float* w0 = Wf + WF_W2 + (4 * kq + 0) * 64;
        const float* w1 = Wf + WF_W2 + (4 * kq + 1) * 64;
        const float* w2 = Wf + WF_W2 + (4 * kq + 2) * 64;
        const float* w3 = Wf + WF_W2 + (4 * kq + 3) * 64;
        #pragma unroll
        for (int j = 0; j < 64; ++j) {
            float acc = y[j];
            acc = fmaf(h0, w0[j], acc);
            acc = fmaf(h1, w1[j], acc);
            acc = fmaf(h2, w2[j], acc);
            acc = fmaf(h3, w3[j], acc);
            y[j] = acc;
        }
    }
    // LayerNorm 2 + relu + W3 dot
    s0 = s1 = s2 = s3 = q0 = q1 = q2 = q3 = 0;
    #pragma unroll
    for (int j = 0; j < 64; j += 4) {
        s0 += y[j];     q0 = fmaf(y[j],     y[j],     q0);
        s1 += y[j + 1]; q1 = fmaf(y[j + 1], y[j + 1], q1);
        s2 += y[j + 2]; q2 = fmaf(y[j + 2], y[j + 2], q2);
        s3 += y[j + 3]; q3 = fmaf(y[j + 3], y[j + 3], q3);
    }
    mu  = ((s0 + s1) + (s2 + s3)) * (1.f / 64.f);
    ex2 = ((q0 + q1) + (q2 + q3)) * (1.f / 64.f);
    float rs2 = rsqrtf(ex2 - mu * mu + LN_EPS);
    float nmrs2 = -mu * rs2;
    float o0 = 0, o1 = 0, o2 = 0, o3 = 0;
    #pragma unroll
    for (int j = 0; j < 64; j += 4) {
        float t0 = fmaxf(fmaf(fmaf(y[j],     rs2, nmrs2), Wf[WF_G2 + j],     Wf[WF_BE2 + j]),     0.f);
        float t1 = fmaxf(fmaf(fmaf(y[j + 1], rs2, nmrs2), Wf[WF_G2 + j + 1], Wf[WF_BE2 + j + 1]), 0.f);
        float t2 = fmaxf(fmaf(fmaf(y[j + 2], rs2, nmrs2), Wf[WF_G2 + j + 2], Wf[WF_BE2 + j + 2]), 0.f);
        float t3 = fmaxf(fmaf(fmaf(y[j + 3], rs2, nmrs2), Wf[WF_G2 + j + 3], Wf[WF_BE2 + j + 3]), 0.f);
        o0 = fmaf(t0, Wf[WF_W3 + j],     o0);
        o1 = fmaf(t1, Wf[WF_W3 + j + 1], o1);
        o2 = fmaf(t2, Wf[WF_W3 + j + 2], o2);
        o3 = fmaf(t3, Wf[WF_W3 + j + 3], o3);
    }
    float o = ((o0 + o1) + (o2 + o3)) + Wf[WF_B3];
    if (isf32) ((float*)out)[b] = o;
    else       ((bf16*)out)[b] = __float2bfloat16(o);
}

extern "C" __attribute__((visibility("default")))
void kernel_launch(void* const* d_in, const int* in_sizes, int n_in,
                   void* d_out, int out_size, void* d_ws, size_t ws_size,
                   hipStream_t stream) {
    const void* uE   = d_in[0];
    const void* iE   = d_in[1];
    const void* uHy  = d_in[2];
    const void* iHy  = d_in[3];
    const void* W1   = d_in[4];
    const void* b1   = d_in[5];
    const void* g1   = d_in[6];
    const void* be1  = d_in[7];
    const void* W2   = d_in[8];
    const void* b2   = d_in[9];
    const void* g2   = d_in[10];
    const void* be2  = d_in[11];
    const void* W3   = d_in[12];
    const void* b3   = d_in[13];
    const void* adj_vals = d_in[14];
    const int*  adj_rows = (const int*)d_in[15];
    const int*  adj_cols = (const int*)d_in[16];
    const int*  userIdx  = (const int*)d_in[17];
    const int*  servIdx  = (const int*)d_in[18];

    char* w = (char*)d_ws;
    size_t off = 0;
    auto alloc = [&](size_t bytes) -> char* {
        char* p = w + off;
        off += (bytes + 255) & ~(size_t)255;
        return p;
    };
    float* E0      = (float*)alloc((size_t)N_CNT * D_DIM * 4);
    float* E1      = (float*)alloc((size_t)N_CNT * D_DIM * 4);
    float* P       = (float*)alloc((size_t)2 * D_DIM * H_DIM * 4);
    float* A       = (float*)alloc((size_t)N_CNT * H_DIM * 4);
    int2*  csr     = (int2*)alloc((size_t)M_EDGE * 8);
    int*   row_ptr = (int*)alloc((size_t)(N_CNT + 1) * 4);
    int*   counts  = (int*)alloc((size_t)N_CNT * 4);
    int*   fill    = (int*)alloc((size_t)N_CNT * 4);
    int*   flag    = (int*)alloc(256);
    float* Wf      = (float*)alloc((size_t)WF_TOT * 4);

    k_init<<<(N_CNT + 255) / 256, 256, 0, stream>>>(uE, counts, fill, flag);
    k_pre<<<(N_CNT * D_DIM + 255) / 256, 256, 0, stream>>>(uE, iE, E0, adj_rows, counts, flag);
    k_scan<<<1, 256, 0, stream>>>(counts, row_ptr);
    k_scatter<<<(M_EDGE + 255) / 256, 256, 0, stream>>>(adj_rows, adj_cols, adj_vals,
                                                        row_ptr, fill, csr, flag);
    // 3 propagation hops: E0 -> E1 -> E0 -> E1
    k_spmm<<<N_CNT, 256, 0, stream>>>((const float2*)E0, (float2*)E1, row_ptr, csr);
    k_spmm<<<N_CNT, 256, 0, stream>>>((const float2*)E1, (float2*)E0, row_ptr, csr);
    k_spmm<<<N_CNT, 256, 0, stream>>>((const float2*)E0, (float2*)E1, row_ptr, csr);

    k_hyperP<<<3, 256, 0, stream>>>(uHy, iHy, W1, W2, b1, g1, be1, b2, g2, be2, W3, b3,
                                    P, Wf, flag);
    k_A<<<N_CNT, H_DIM, 0, stream>>>(E1, P, Wf, A);

    HyperModel_65755949301857_kernel<<<(B_CNT + 255) / 256, 256, 0, stream>>>(
        A, userIdx, servIdx, Wf, d_out, flag);
}